// Round 17
// baseline (587.659 us; speedup 1.0000x reference)
//
#include <hip/hip_runtime.h>
#include <cstdint>
#include <cstddef>

typedef unsigned short u16;
typedef short short8 __attribute__((ext_vector_type(8)));
typedef float f32x4 __attribute__((ext_vector_type(4)));

__device__ __forceinline__ u16 f2bf(float f) {
  union { float f; unsigned u; } x; x.f = f;
  unsigned r = x.u + 0x7FFFu + ((x.u >> 16) & 1u);   // RNE
  return (u16)(r >> 16);
}
__device__ __forceinline__ float b2f(u16 h) {
  union { unsigned u; float f; } x; x.u = ((unsigned)h) << 16;
  return x.f;
}
__device__ __forceinline__ float silu_f(float v) {
  return v / (1.f + __expf(-v));
}
__device__ __forceinline__ void gll(const u16* g, u16* l) {
  __builtin_amdgcn_global_load_lds((const __attribute__((address_space(1))) unsigned*)g,
                                   (__attribute__((address_space(3))) unsigned*)l, 16, 0, 0);
}
__device__ __forceinline__ short8 ld8(const u16* p) { return *(const short8*)p; }

// ---------------- fused f32 -> bf16 conversion for 6 inputs (x..W_post) ----------------
__global__ __launch_bounds__(256) void cvt7_k(const float4* __restrict__ s0,
                                              const float4* __restrict__ s1,
                                              const float4* __restrict__ s2,
                                              const float4* __restrict__ s3,
                                              const float4* __restrict__ s4,
                                              const float4* __restrict__ s5,
                                              ushort4* __restrict__ dst) {
  const int i = blockIdx.x * 256 + threadIdx.x;
  const int o1 = 4194304, o2 = 6291456, o3 = 8388608, o4 = 10485760,
            o5 = 10616832, o6 = 10878976;
  if (i >= o6) return;
  const float4* src;
  int base;
  if      (i < o1) { src = s0; base = 0;  }
  else if (i < o2) { src = s1; base = o1; }
  else if (i < o3) { src = s2; base = o2; }
  else if (i < o4) { src = s3; base = o3; }
  else if (i < o5) { src = s4; base = o4; }
  else             { src = s5; base = o5; }
  float4 v = src[i - base];
  ushort4 o;
  o.x = f2bf(v.x); o.y = f2bf(v.y); o.z = f2bf(v.z); o.w = f2bf(v.w);
  dst[i] = o;
}

// ------- W_proj [4096][256] f32 -> WprojT [256][4096] bf16 (LDS-tiled, coalesced) -------
__global__ __launch_bounds__(256) void tcvt_k(const float* __restrict__ in,
                                              u16* __restrict__ out) {
  __shared__ float t[64][65];
  const int h0 = blockIdx.x * 64, a0 = blockIdx.y * 64;
  const int c = threadIdx.x & 63, g = threadIdx.x >> 6;
#pragma unroll
  for (int i = 0; i < 16; ++i) {
    int r = g * 16 + i;
    t[r][c] = in[(size_t)(h0 + r) * 256 + a0 + c];
  }
  __syncthreads();
#pragma unroll
  for (int i = 0; i < 16; ++i) {
    int a = g * 16 + i;
    out[(size_t)(a0 + a) * 4096 + h0 + c] = f2bf(t[c][a]);
  }
}

// ---------------- reduce 4 split-K partials + LayerNorm over 256 cols ----------------
__global__ __launch_bounds__(256) void red_ln_k(const float* __restrict__ part,
                                                const float* __restrict__ g,
                                                const float* __restrict__ b,
                                                u16* __restrict__ out,
                                                u16* __restrict__ outT, int Mtot) {
  const int row = blockIdx.x;
  const int a = threadIdx.x;
  const size_t stride = (size_t)Mtot * 256;
  const size_t base = (size_t)row * 256 + a;
  float v = part[base] + part[base + stride] + part[base + 2 * stride] + part[base + 3 * stride];
  float s = v, s2 = v * v;
#pragma unroll
  for (int o = 32; o; o >>= 1) { s += __shfl_down(s, o, 64); s2 += __shfl_down(s2, o, 64); }
  __shared__ float red[8];
  int l = a & 63, w = a >> 6;
  if (l == 0) { red[w] = s; red[4 + w] = s2; }
  __syncthreads();
  s  = red[0] + red[1] + red[2] + red[3];
  s2 = red[4] + red[5] + red[6] + red[7];
  float mu  = s * 0.00390625f;
  float var = s2 * 0.00390625f - mu * mu;
  float rs  = rsqrtf(var + 1e-5f);
  float o   = (v - mu) * rs * g[a] + b[a];
  u16 ob = f2bf(o);
  out[base] = ob;
  if (outT) {
    int bi = row >> 11, t = row & 2047;
    outT[((size_t)bi * 256 + a) * 2048 + t] = ob;
  }
}

// ---------------- reduce SK split-K partials -> bf16 (with scale) ----------------
template <int SK>
__global__ __launch_bounds__(256) void red_k(const float* __restrict__ part,
                                             u16* __restrict__ out, int Mtot, float scale) {
  const int row = blockIdx.x;
  const int a = threadIdx.x;
  const size_t stride = (size_t)Mtot * 256;
  const size_t base = (size_t)row * 256 + a;
  float v = 0.f;
#pragma unroll
  for (int s = 0; s < SK; ++s) v += part[base + (size_t)s * stride];
  out[base] = f2bf(v * scale);
}

// ================= 128x128 split-K partial GEMM, T2-swizzled: f32 partials =================
template <int SK>
__global__ __launch_bounds__(256) void gemm_sk(const u16* __restrict__ A,
                                               const u16* __restrict__ B,
                                               float* __restrict__ part,
                                               int M, int N, int Kfull, int Kc,
                                               long bA, long bB, int Mtot) {
  const int z  = blockIdx.z;
  const int b  = z / SK, sk = z % SK;
  const int brow = blockIdx.y * 128;
  const int bcol = blockIdx.x * 128;
  A += (size_t)b * bA + (size_t)sk * Kc;
  B += (size_t)b * bB + (size_t)sk * Kc;

  __shared__ u16 Al[128 * 64];
  __shared__ u16 Bl[128 * 64];
  const int tid  = threadIdx.x;
  const int lane = tid & 63;
  const int w = tid >> 6, wr = w >> 1, wc = w & 1;
  const int srow = tid >> 3;
  const int scol = (((tid & 7) ^ (srow & 7)) * 8);
  const int fr   = lane & 15;
  const int kg   = lane >> 4;

  f32x4 acc[4][4] = {};

  for (int kt = 0; kt < Kc; kt += 64) {
#pragma unroll
    for (int i = 0; i < 4; ++i)
      gll(A + (size_t)(brow + i * 32 + srow) * Kfull + kt + scol, &Al[(i * 256 + tid) * 8]);
#pragma unroll
    for (int i = 0; i < 4; ++i)
      gll(B + (size_t)(bcol + i * 32 + srow) * Kfull + kt + scol, &Bl[(i * 256 + tid) * 8]);
    __syncthreads();
#pragma unroll
    for (int kk = 0; kk < 2; ++kk) {
      short8 af[4], bfr[4];
      const int ko8 = kk * 4 + kg;
#pragma unroll
      for (int m = 0; m < 4; ++m) {
        const int r = wr * 64 + m * 16 + fr;
        af[m] = ld8(&Al[r * 64 + ((ko8 ^ (fr & 7)) << 3)]);
      }
#pragma unroll
      for (int n = 0; n < 4; ++n) {
        const int r = wc * 64 + n * 16 + fr;
        bfr[n] = ld8(&Bl[r * 64 + ((ko8 ^ (fr & 7)) << 3)]);
      }
#pragma unroll
      for (int m = 0; m < 4; ++m)
#pragma unroll
        for (int n = 0; n < 4; ++n)
          acc[m][n] = __builtin_amdgcn_mfma_f32_16x16x32_bf16(af[m], bfr[n], acc[m][n], 0, 0, 0);
    }
    __syncthreads();
  }

  const int col0 = bcol + wc * 64 + fr;
  const int row0 = brow + wr * 64 + (kg << 2);
  float* P = part + ((size_t)sk * Mtot + (size_t)b * M) * N;
#pragma unroll
  for (int m = 0; m < 4; ++m)
#pragma unroll
    for (int j = 0; j < 4; ++j) {
      size_t roff = (size_t)(row0 + m * 16 + j) * N + col0;
#pragma unroll
      for (int n = 0; n < 4; ++n) P[roff + n * 16] = acc[m][n][j];
    }
}

// ================= 256x256 8-wave pipeline, BK=32, 3-deep LDS, ONE barrier/tile ==========
// Tile = one phase: {read 12 frags (B first); stage tile t+2 (4 gll); 32 MFMA; fence; barrier}.
// 3 buffers: stage(t+2) -> buf (t+2)%3, whose last reader finished at end of tile t-1
// (one barrier before the stage — same WAR protection as the r16 schedule).
// Ledger (4 gll/stage): prologue stage(0),stage(1) -> vmcnt(4) keeps stage(1).
// Steady: after stage(t+2), 8 in flight -> vmcnt(4) drains stage(t+1) (needed next tile),
// keeps stage(t+2). Tails: t+1<NT -> vmcnt(0); last tile none.
// Swizzle (BK=32, 64B row stride): store col-chunk c ^= (row>>1)&3 (inverse applied on the
// global source: (tid&3)^((tid>>3)&3)); read slot (lane>>4)^((lane>>1)&3) -> 8 lanes per
// 16B slot = minimum LDS cycles (conflict-free).
__device__ __forceinline__ void pipe32(const u16* Asrc, const u16* Bsrc, int K,
                                       u16* As, u16* Bs, int tid, int wm, int wn,
                                       int lane, f32x4 (*acc)[4], size_t bOff2) {
  const int NT = K >> 5;

  auto stage = [&](int tt) {
    const int b = tt % 3;
    const u16* sa = Asrc + (tt << 5);
    const u16* sb = Bsrc + (tt << 5);
    u16* da = &As[b * 8192 + tid * 8];
    u16* db = &Bs[b * 8192 + tid * 8];
    gll(sa, da); gll(sa + (size_t)128 * K, da + 4096);
    gll(sb, db); gll(sb + bOff2, db + 4096);
  };

  stage(0);
  if (NT > 1) {
    stage(1);
    asm volatile("s_waitcnt vmcnt(4)" ::: "memory");
  } else {
    asm volatile("s_waitcnt vmcnt(0)" ::: "memory");
  }
  __builtin_amdgcn_s_barrier();

  const int rb = (lane & 15) * 32 + ((((lane >> 4) ^ ((lane >> 1) & 3))) << 3);
  short8 af[8], bf2[4];

  for (int t = 0; t < NT; ++t) {
    const int cb = t % 3;
    const u16* aB = &As[cb * 8192];
    const u16* bB = &Bs[cb * 8192];

    // reads: B frags first (earliest MFMA deps), then A frags
#pragma unroll
    for (int n = 0; n < 4; ++n) {
      const int off = (n < 2) ? (wn * 1024 + n * 512) : (4096 + wn * 1024 + (n - 2) * 512);
      bf2[n] = ld8(bB + off + rb);
    }
#pragma unroll
    for (int m = 0; m < 8; ++m) {
      const int off = (m < 4) ? (wm * 2048 + m * 512) : (4096 + wm * 2048 + (m - 4) * 512);
      af[m] = ld8(aB + off + rb);
    }
    if (t + 2 < NT) stage(t + 2);
    __builtin_amdgcn_s_setprio(1);
#pragma unroll
    for (int m = 0; m < 8; ++m)
#pragma unroll
      for (int n = 0; n < 4; ++n)
        acc[m][n] = __builtin_amdgcn_mfma_f32_16x16x32_bf16(af[m], bf2[n], acc[m][n], 0, 0, 0);
    __builtin_amdgcn_s_setprio(0);
    if (t + 2 < NT)      { asm volatile("s_waitcnt vmcnt(4)" ::: "memory"); }
    else if (t + 1 < NT) { asm volatile("s_waitcnt vmcnt(0)" ::: "memory"); }
    __builtin_amdgcn_s_barrier();
  }
}

// EPI: 0=f32 store, 2=silu(clip(v,-5,5)) bf16 store, 5=fused up/gate (N-half tile).
// Batched via blockIdx.z with strides bA/bB/bC. Optional second K-segment (A2,B2,K2).
template <int EPI>
__global__ __launch_bounds__(512, 2) void gemm256(const u16* __restrict__ A,
                                                  const u16* __restrict__ B,
                                                  void* __restrict__ Cv,
                                                  int N, int K,
                                                  const u16* __restrict__ A2,
                                                  const u16* __restrict__ B2, int K2,
                                                  long bA, long bB, long bC) {
  __shared__ __align__(16) u16 As[24576];   // [3 buf][256][32] u16 = 48 KB
  __shared__ __align__(16) u16 Bs[24576];
  const int tid = threadIdx.x;
  const int bz  = blockIdx.z;
  A += (size_t)bz * bA;
  B += (size_t)bz * bB;

  // T1: bijective XCD swizzle (m204)
  const int gx = gridDim.x;
  const int nwg = gx * gridDim.y;
  int orig = blockIdx.y * gx + blockIdx.x;
  {
    int q = nwg >> 3, r = nwg & 7;
    int xcd = orig & 7, idx = orig >> 3;
    orig = (xcd < r) ? xcd * (q + 1) + idx : r * (q + 1) + (xcd - r) * q + idx;
  }
  const int brow = (orig / gx) * 256;
  const int bcol = (orig % gx) * ((EPI == 5) ? 128 : 256);
  const int bHalfOff = (EPI == 5) ? 4096 : 128;

  const int lane = tid & 63;
  const int wid  = tid >> 6;
  const int wm = wid >> 2, wn = wid & 3;
  const int srow2 = tid >> 2;
  const int scol2 = ((tid & 3) ^ ((tid >> 3) & 3)) << 3;   // swizzled source col chunk (u16)

  f32x4 acc[8][4] = {};

  pipe32(A + (size_t)(brow + srow2) * K + scol2,
         B + (size_t)(bcol + srow2) * K + scol2, K, As, Bs, tid, wm, wn, lane, acc,
         (size_t)bHalfOff * K);
  if (K2 > 0)
    pipe32(A2 + (size_t)(brow + srow2) * K2 + scol2,
           B2 + (size_t)(bcol + srow2) * K2 + scol2, K2, As, Bs, tid, wm, wn, lane, acc,
           (size_t)128 * K2);

  const int fr = lane & 15;
  if (EPI == 0 || EPI == 2) {
#pragma unroll
    for (int m = 0; m < 8; ++m) {
      const int mrow = (m < 4) ? (wm * 64 + m * 16) : (128 + wm * 64 + (m - 4) * 16);
#pragma unroll
      for (int j = 0; j < 4; ++j) {
        const size_t roff = (size_t)(brow + mrow + ((lane >> 4) << 2) + j) * N + bcol + fr;
#pragma unroll
        for (int n = 0; n < 4; ++n) {
          const int ncol = (n < 2) ? (wn * 32 + n * 16) : (128 + wn * 32 + (n - 2) * 16);
          if (EPI == 0) {
            ((float*)Cv + (size_t)bz * bC)[roff + ncol] = acc[m][n][j];
          } else {
            float v = acc[m][n][j];
            v = fminf(5.f, fmaxf(-5.f, v));
            ((u16*)Cv + (size_t)bz * bC)[roff + ncol] = f2bf(silu_f(v));
          }
        }
      }
    }
  } else {  // EPI == 5: up = acc[m][n], gate = acc[m][n+2]; write bf16 hidden (stride N)
    u16* Cb = (u16*)Cv;
#pragma unroll
    for (int m = 0; m < 8; ++m) {
      const int mrow = (m < 4) ? (wm * 64 + m * 16) : (128 + wm * 64 + (m - 4) * 16);
#pragma unroll
      for (int j = 0; j < 4; ++j) {
        const size_t roff = (size_t)(brow + mrow + ((lane >> 4) << 2) + j) * N + bcol + wn * 32 + fr;
#pragma unroll
        for (int n = 0; n < 2; ++n)
          Cb[roff + n * 16] = f2bf(silu_f(acc[m][n + 2][j]) * acc[m][n][j]);
      }
    }
  }
}

extern "C" void kernel_launch(void* const* d_in, const int* in_sizes, int n_in,
                              void* d_out, int out_size, void* d_ws, size_t ws_size,
                              hipStream_t stream) {
  const float* x      = (const float*)d_in[0];
  const float* W_up   = (const float*)d_in[1];
  const float* W_gate = (const float*)d_in[2];
  const float* W_down = (const float*)d_in[3];
  const float* W_pre  = (const float*)d_in[4];
  const float* W_post = (const float*)d_in[5];
  const float* W_proj = (const float*)d_in[6];
  const float* ln_g   = (const float*)d_in[7];
  const float* ln_b   = (const float*)d_in[8];
  (void)in_sizes; (void)n_in; (void)out_size; (void)ws_size;

  const int D = 2048, Hh = 4096, A_ = 256, Bn = 4, S = 2048, M = 8192;

  char* p = (char*)d_ws;
  u16* xb      = (u16*)p; p += (size_t)M * D * 2;
  u16* Wug_b   = (u16*)p; p += (size_t)2 * Hh * D * 2;  // [8192][2048]: rows 0-4095 up, 4096-8191 gate
  u16* Wdown_b = (u16*)p; p += (size_t)D * Hh * 2;
  u16* Wpre_b  = (u16*)p; p += (size_t)A_ * D * 2;
  u16* Wpost_b = (u16*)p; p += (size_t)A_ * Hh * 2;
  u16* WprojT  = (u16*)p; p += (size_t)Hh * A_ * 2;     // [256][4096] bf16 (transposed)
  u16* hidden  = (u16*)p; p += (size_t)M * Hh * 2;
  u16* scratch = (u16*)p; p += (size_t)M * Hh * 2;
  char* q = (char*)scratch;
  u16*   aw        = (u16*)q; q += (size_t)Bn * S * S * 2;
  u16*   adapt_in  = (u16*)q; q += (size_t)M * A_ * 2;
  u16*   adapt_inT = (u16*)q; q += (size_t)M * A_ * 2;
  u16*   adapt_out = (u16*)q; q += (size_t)M * A_ * 2;
  u16*   adaptb    = (u16*)q; q += (size_t)M * A_ * 2;
  u16*   Wdp_b     = (u16*)q; q += (size_t)2048 * 256 * 2;   // [2048][256] bf16 (0.1 folded)
  float* part     = (float*)Wug_b;    // [4][8192][256] f32 — alias Wug (dead after upgate GEMM)
  float* wdp_part = (float*)hidden;   // [8][2048][256] f32 — alias hidden (dead until upgate)

  // conversions (Wug = W_up then W_gate, contiguous)
  cvt7_k<<<dim3(42496), dim3(256), 0, stream>>>((const float4*)x, (const float4*)W_up,
                                                (const float4*)W_gate, (const float4*)W_down,
                                                (const float4*)W_pre, (const float4*)W_post,
                                                (ushort4*)xb);
  tcvt_k<<<dim3(64, 4), dim3(256), 0, stream>>>(W_proj, WprojT);

  // Wdp = 0.1 * (W_down @ W_proj)  [2048,256] — split-K(8) over K=4096
  gemm_sk<8><<<dim3(A_ / 128, 2048 / 128, 8), 256, 0, stream>>>(Wdown_b, WprojT, wdp_part,
                                                                2048, A_, Hh, Hh / 8, 0, 0, 2048);
  red_k<8><<<dim3(2048), 256, 0, stream>>>(wdp_part, Wdp_b, 2048, 0.1f);

  // hidden = silu(x @ W_gate^T) * (x @ W_up^T)  — single fused GEMM (EPI5)
  gemm256<5><<<dim3(Hh / 128, M / 256), 512, 0, stream>>>(xb, Wug_b, hidden,
                                                          Hh, D, nullptr, nullptr, 0, 0, 0, 0);

  // adapt_in = LN(x @ W_pre^T)  — split-K(4) + fused reduce/LN
  gemm_sk<4><<<dim3(A_ / 128, M / 128, 4), 256, 0, stream>>>(xb, Wpre_b, part,
                                                             M, A_, D, D / 4, 0, 0, M);
  red_ln_k<<<dim3(M), 256, 0, stream>>>(part, ln_g, ln_b, adapt_in, adapt_inT, M);

  // adapt_out = LN(hidden @ W_post^T)  — split-K(4)
  gemm_sk<4><<<dim3(A_ / 128, M / 128, 4), 256, 0, stream>>>(hidden, Wpost_b, part,
                                                             M, A_, Hh, Hh / 4, 0, 0, M);
  red_ln_k<<<dim3(M), 256, 0, stream>>>(part, ln_g, ln_b, adapt_out, nullptr, M);

  // aw[b] = silu(clip(adapt_in[b] @ adapt_out[b]^T, -5, 5))  — 256² pipeline, batched
  gemm256<2><<<dim3(S / 256, S / 256, Bn), 512, 0, stream>>>(adapt_in, adapt_out, aw,
                                                             S, A_, nullptr, nullptr, 0,
                                                             (long)S * A_, (long)S * A_,
                                                             (long)S * S);

  // adapt[b] = aw[b] @ adapt_in[b]  — split-K(4) over K=S, batched
  gemm_sk<4><<<dim3(A_ / 128, S / 128, Bn * 4), 256, 0, stream>>>(aw, adapt_inT, part,
                                                                  S, A_, S, S / 4,
                                                                  (long)S * S, (long)A_ * S, M);
  red_k<4><<<dim3(M), 256, 0, stream>>>(part, adaptb, M, 1.0f);

  // out = hidden @ W_down^T + adaptb @ Wdp^T   [M,D] f32  (dual-K pipeline)
  gemm256<0><<<dim3(D / 256, M / 256), 512, 0, stream>>>(hidden, Wdown_b, d_out,
                                                         D, Hh, adaptb, Wdp_b, A_, 0, 0, 0);
}

// Round 18
// 559.676 us; speedup vs baseline: 1.0500x; 1.0500x over previous
//
#include <hip/hip_runtime.h>
#include <cstdint>
#include <cstddef>

typedef unsigned short u16;
typedef short short8 __attribute__((ext_vector_type(8)));
typedef float f32x4 __attribute__((ext_vector_type(4)));

__device__ __forceinline__ u16 f2bf(float f) {
  union { float f; unsigned u; } x; x.f = f;
  unsigned r = x.u + 0x7FFFu + ((x.u >> 16) & 1u);   // RNE
  return (u16)(r >> 16);
}
__device__ __forceinline__ float b2f(u16 h) {
  union { unsigned u; float f; } x; x.u = ((unsigned)h) << 16;
  return x.f;
}
__device__ __forceinline__ float silu_f(float v) {
  return v / (1.f + __expf(-v));
}
__device__ __forceinline__ void gll(const u16* g, u16* l) {
  __builtin_amdgcn_global_load_lds((const __attribute__((address_space(1))) unsigned*)g,
                                   (__attribute__((address_space(3))) unsigned*)l, 16, 0, 0);
}
__device__ __forceinline__ short8 ld8(const u16* p) { return *(const short8*)p; }

// ---------------- fused f32 -> bf16 conversion for 6 inputs (x..W_post) ----------------
__global__ __launch_bounds__(256) void cvt7_k(const float4* __restrict__ s0,
                                              const float4* __restrict__ s1,
                                              const float4* __restrict__ s2,
                                              const float4* __restrict__ s3,
                                              const float4* __restrict__ s4,
                                              const float4* __restrict__ s5,
                                              ushort4* __restrict__ dst) {
  const int i = blockIdx.x * 256 + threadIdx.x;
  const int o1 = 4194304, o2 = 6291456, o3 = 8388608, o4 = 10485760,
            o5 = 10616832, o6 = 10878976;
  if (i >= o6) return;
  const float4* src;
  int base;
  if      (i < o1) { src = s0; base = 0;  }
  else if (i < o2) { src = s1; base = o1; }
  else if (i < o3) { src = s2; base = o2; }
  else if (i < o4) { src = s3; base = o3; }
  else if (i < o5) { src = s4; base = o4; }
  else             { src = s5; base = o5; }
  float4 v = src[i - base];
  ushort4 o;
  o.x = f2bf(v.x); o.y = f2bf(v.y); o.z = f2bf(v.z); o.w = f2bf(v.w);
  dst[i] = o;
}

// ------- W_proj [4096][256] f32 -> WprojT [256][4096] bf16 (LDS-tiled, coalesced) -------
__global__ __launch_bounds__(256) void tcvt_k(const float* __restrict__ in,
                                              u16* __restrict__ out) {
  __shared__ float t[64][65];
  const int h0 = blockIdx.x * 64, a0 = blockIdx.y * 64;
  const int c = threadIdx.x & 63, g = threadIdx.x >> 6;
#pragma unroll
  for (int i = 0; i < 16; ++i) {
    int r = g * 16 + i;
    t[r][c] = in[(size_t)(h0 + r) * 256 + a0 + c];
  }
  __syncthreads();
#pragma unroll
  for (int i = 0; i < 16; ++i) {
    int a = g * 16 + i;
    out[(size_t)(a0 + a) * 4096 + h0 + c] = f2bf(t[c][a]);
  }
}

// ---------------- reduce 4 split-K partials + LayerNorm over 256 cols ----------------
__global__ __launch_bounds__(256) void red_ln_k(const float* __restrict__ part,
                                                const float* __restrict__ g,
                                                const float* __restrict__ b,
                                                u16* __restrict__ out,
                                                u16* __restrict__ outT, int Mtot) {
  const int row = blockIdx.x;
  const int a = threadIdx.x;
  const size_t stride = (size_t)Mtot * 256;
  const size_t base = (size_t)row * 256 + a;
  float v = part[base] + part[base + stride] + part[base + 2 * stride] + part[base + 3 * stride];
  float s = v, s2 = v * v;
#pragma unroll
  for (int o = 32; o; o >>= 1) { s += __shfl_down(s, o, 64); s2 += __shfl_down(s2, o, 64); }
  __shared__ float red[8];
  int l = a & 63, w = a >> 6;
  if (l == 0) { red[w] = s; red[4 + w] = s2; }
  __syncthreads();
  s  = red[0] + red[1] + red[2] + red[3];
  s2 = red[4] + red[5] + red[6] + red[7];
  float mu  = s * 0.00390625f;
  float var = s2 * 0.00390625f - mu * mu;
  float rs  = rsqrtf(var + 1e-5f);
  float o   = (v - mu) * rs * g[a] + b[a];
  u16 ob = f2bf(o);
  out[base] = ob;
  if (outT) {
    int bi = row >> 11, t = row & 2047;
    outT[((size_t)bi * 256 + a) * 2048 + t] = ob;
  }
}

// ---------------- reduce SK split-K partials -> bf16 (with scale) ----------------
template <int SK>
__global__ __launch_bounds__(256) void red_k(const float* __restrict__ part,
                                             u16* __restrict__ out, int Mtot, float scale) {
  const int row = blockIdx.x;
  const int a = threadIdx.x;
  const size_t stride = (size_t)Mtot * 256;
  const size_t base = (size_t)row * 256 + a;
  float v = 0.f;
#pragma unroll
  for (int s = 0; s < SK; ++s) v += part[base + (size_t)s * stride];
  out[base] = f2bf(v * scale);
}

// ================= 128x128 split-K partial GEMM, T2-swizzled: f32 partials =================
template <int SK>
__global__ __launch_bounds__(256) void gemm_sk(const u16* __restrict__ A,
                                               const u16* __restrict__ B,
                                               float* __restrict__ part,
                                               int M, int N, int Kfull, int Kc,
                                               long bA, long bB, int Mtot) {
  const int z  = blockIdx.z;
  const int b  = z / SK, sk = z % SK;
  const int brow = blockIdx.y * 128;
  const int bcol = blockIdx.x * 128;
  A += (size_t)b * bA + (size_t)sk * Kc;
  B += (size_t)b * bB + (size_t)sk * Kc;

  __shared__ u16 Al[128 * 64];
  __shared__ u16 Bl[128 * 64];
  const int tid  = threadIdx.x;
  const int lane = tid & 63;
  const int w = tid >> 6, wr = w >> 1, wc = w & 1;
  const int srow = tid >> 3;
  const int scol = (((tid & 7) ^ (srow & 7)) * 8);
  const int fr   = lane & 15;
  const int kg   = lane >> 4;

  f32x4 acc[4][4] = {};

  for (int kt = 0; kt < Kc; kt += 64) {
#pragma unroll
    for (int i = 0; i < 4; ++i)
      gll(A + (size_t)(brow + i * 32 + srow) * Kfull + kt + scol, &Al[(i * 256 + tid) * 8]);
#pragma unroll
    for (int i = 0; i < 4; ++i)
      gll(B + (size_t)(bcol + i * 32 + srow) * Kfull + kt + scol, &Bl[(i * 256 + tid) * 8]);
    __syncthreads();
#pragma unroll
    for (int kk = 0; kk < 2; ++kk) {
      short8 af[4], bfr[4];
      const int ko8 = kk * 4 + kg;
#pragma unroll
      for (int m = 0; m < 4; ++m) {
        const int r = wr * 64 + m * 16 + fr;
        af[m] = ld8(&Al[r * 64 + ((ko8 ^ (fr & 7)) << 3)]);
      }
#pragma unroll
      for (int n = 0; n < 4; ++n) {
        const int r = wc * 64 + n * 16 + fr;
        bfr[n] = ld8(&Bl[r * 64 + ((ko8 ^ (fr & 7)) << 3)]);
      }
#pragma unroll
      for (int m = 0; m < 4; ++m)
#pragma unroll
        for (int n = 0; n < 4; ++n)
          acc[m][n] = __builtin_amdgcn_mfma_f32_16x16x32_bf16(af[m], bfr[n], acc[m][n], 0, 0, 0);
    }
    __syncthreads();
  }

  const int col0 = bcol + wc * 64 + fr;
  const int row0 = brow + wr * 64 + (kg << 2);
  float* P = part + ((size_t)sk * Mtot + (size_t)b * M) * N;
#pragma unroll
  for (int m = 0; m < 4; ++m)
#pragma unroll
    for (int j = 0; j < 4; ++j) {
      size_t roff = (size_t)(row0 + m * 16 + j) * N + col0;
#pragma unroll
      for (int n = 0; n < 4; ++n) P[roff + n * 16] = acc[m][n][j];
    }
}

// ================= 256x256 quadrant-staggered 8-wave pipeline, THREE barriers/tile ======
// (round-16 verified best: upgate 255us, MfmaUtil 48.5%, total 560.8us)
// ph1 = {read aLo(8)+bb(4, B-lo); stage B1(t+1); 16 MFMA acc[0-3][0-1]; barrier}
// ph2 = {read aHi(8); stage A0,B0(t+2); 16 MFMA acc[4-7][0-1]; fence; barrier}
// ph3'= {read bb(4, B-hi); stage A1(t+2); 32 MFMA acc[0-7][2-3]; fence; barrier}
// Reads precede stages (stage-first adds compiler alias-waits: r15 regression).
// Ledger: entering-tile invariant 8 = {B1(t),A0B0(t+1),A1(t+1)}.
// ph2-end: pf2 -> vmcnt(12) drains B1(t); tail t+1<NT -> vmcnt(8); last -> vmcnt(0).
// ph3'-end: pf2 -> vmcnt(8) drains A0B0,A1(t+1); tail t+1<NT -> vmcnt(0).
__device__ __forceinline__ void pipe256(const u16* Abase, const u16* Bbase, int K,
                                        u16* As, u16* Bs, int tid, int wm, int wn,
                                        int lane, f32x4 (*acc)[4], int bHalfOff) {
  const int fr  = lane & 15;
  const int cs0 = ((((lane >> 4) << 4) ^ ((lane & 7) << 4)) >> 1);
  const int cs1 = cs0 ^ 32;
  const int NT = K >> 6;

  auto stageA = [&](int tt, int half) {
    const u16* s = Abase + (size_t)(half * 128) * K + (tt << 6);
    u16* d = &As[((tt & 1) * 2 + half) * 8192 + tid * 8];
    gll(s, d); gll(s + (size_t)64 * K, d + 4096);
  };
  auto stageB = [&](int tt, int half) {
    const u16* s = Bbase + (size_t)half * bHalfOff * K + (tt << 6);
    u16* d = &Bs[((tt & 1) * 2 + half) * 8192 + tid * 8];
    gll(s, d); gll(s + (size_t)64 * K, d + 4096);
  };

  // prologue: all of tile 0 (8) + A0,B0,A1 of tile 1 (6); B1(1) staged at t=0 ph1
  stageA(0, 0); stageB(0, 0); stageA(0, 1); stageB(0, 1);
  if (NT > 1) {
    stageA(1, 0); stageB(1, 0); stageA(1, 1);
    asm volatile("s_waitcnt vmcnt(6)" ::: "memory");
  } else {
    asm volatile("s_waitcnt vmcnt(0)" ::: "memory");
  }
  __builtin_amdgcn_s_barrier();

  const int aoff0 = (wm * 64 + fr) * 64;
  const int boff0 = (wn * 32 + fr) * 64;

  short8 aLo[8], aHi[8], bb[4];

  for (int t = 0; t < NT; ++t) {
    const u16* h0a = &As[(t & 1) * 16384];
    const u16* h0b = &Bs[(t & 1) * 16384];
    const u16* h1a = h0a + 8192;
    const u16* h1b = h0b + 8192;
    const bool pf2 = (t + 2 < NT);

    // ---------- ph1: read aLo + B-lo; stage B1(t+1); MFMA acc[0-3][0-1]; barrier ----------
#pragma unroll
    for (int m = 0; m < 4; ++m) {
      aLo[m * 2]     = ld8(h0a + aoff0 + m * 1024 + cs0);
      aLo[m * 2 + 1] = ld8(h0a + aoff0 + m * 1024 + cs1);
    }
#pragma unroll
    for (int n = 0; n < 2; ++n) {
      bb[n * 2]     = ld8(h0b + boff0 + n * 1024 + cs0);
      bb[n * 2 + 1] = ld8(h0b + boff0 + n * 1024 + cs1);
    }
    if (t + 1 < NT) stageB(t + 1, 1);
    __builtin_amdgcn_s_setprio(1);
#pragma unroll
    for (int m = 0; m < 4; ++m)
#pragma unroll
      for (int n = 0; n < 2; ++n) {
        acc[m][n] = __builtin_amdgcn_mfma_f32_16x16x32_bf16(aLo[m*2],   bb[n*2],   acc[m][n], 0, 0, 0);
        acc[m][n] = __builtin_amdgcn_mfma_f32_16x16x32_bf16(aLo[m*2+1], bb[n*2+1], acc[m][n], 0, 0, 0);
      }
    __builtin_amdgcn_s_setprio(0);
    __builtin_amdgcn_s_barrier();

    // ---------- ph2: read aHi; stage A0,B0(t+2); MFMA acc[4-7][0-1]; fence; barrier ------
#pragma unroll
    for (int m = 0; m < 4; ++m) {
      aHi[m * 2]     = ld8(h1a + aoff0 + m * 1024 + cs0);
      aHi[m * 2 + 1] = ld8(h1a + aoff0 + m * 1024 + cs1);
    }
    if (pf2) { stageA(t + 2, 0); stageB(t + 2, 0); }
    __builtin_amdgcn_s_setprio(1);
#pragma unroll
    for (int m = 0; m < 4; ++m)
#pragma unroll
      for (int n = 0; n < 2; ++n) {
        acc[4+m][n] = __builtin_amdgcn_mfma_f32_16x16x32_bf16(aHi[m*2],   bb[n*2],   acc[4+m][n], 0, 0, 0);
        acc[4+m][n] = __builtin_amdgcn_mfma_f32_16x16x32_bf16(aHi[m*2+1], bb[n*2+1], acc[4+m][n], 0, 0, 0);
      }
    __builtin_amdgcn_s_setprio(0);
    if (pf2)             { asm volatile("s_waitcnt vmcnt(12)" ::: "memory"); }
    else if (t + 1 < NT) { asm volatile("s_waitcnt vmcnt(8)"  ::: "memory"); }
    else                 { asm volatile("s_waitcnt vmcnt(0)"  ::: "memory"); }
    __builtin_amdgcn_s_barrier();

    // ---------- ph3': read B-hi; stage A1(t+2); 32 MFMA acc[0-7][2-3]; fence; barrier ----
#pragma unroll
    for (int n = 0; n < 2; ++n) {
      bb[n * 2]     = ld8(h1b + boff0 + n * 1024 + cs0);
      bb[n * 2 + 1] = ld8(h1b + boff0 + n * 1024 + cs1);
    }
    if (pf2) stageA(t + 2, 1);
    __builtin_amdgcn_s_setprio(1);
#pragma unroll
    for (int m = 0; m < 4; ++m)
#pragma unroll
      for (int n = 0; n < 2; ++n) {
        acc[m][2+n] = __builtin_amdgcn_mfma_f32_16x16x32_bf16(aLo[m*2],   bb[n*2],   acc[m][2+n], 0, 0, 0);
        acc[m][2+n] = __builtin_amdgcn_mfma_f32_16x16x32_bf16(aLo[m*2+1], bb[n*2+1], acc[m][2+n], 0, 0, 0);
      }
#pragma unroll
    for (int m = 0; m < 4; ++m)
#pragma unroll
      for (int n = 0; n < 2; ++n) {
        acc[4+m][2+n] = __builtin_amdgcn_mfma_f32_16x16x32_bf16(aHi[m*2],   bb[n*2],   acc[4+m][2+n], 0, 0, 0);
        acc[4+m][2+n] = __builtin_amdgcn_mfma_f32_16x16x32_bf16(aHi[m*2+1], bb[n*2+1], acc[4+m][2+n], 0, 0, 0);
      }
    __builtin_amdgcn_s_setprio(0);
    if (pf2)              { asm volatile("s_waitcnt vmcnt(8)" ::: "memory"); }
    else if (t + 1 < NT)  { asm volatile("s_waitcnt vmcnt(0)" ::: "memory"); }
    __builtin_amdgcn_s_barrier();
  }
}

// EPI: 0=f32 store, 2=silu(clip(v,-5,5)) bf16 store, 5=fused up/gate (N-half tile).
// Batched via blockIdx.z with strides bA/bB/bC. Optional second K-segment (A2,B2,K2).
template <int EPI>
__global__ __launch_bounds__(512, 2) void gemm256(const u16* __restrict__ A,
                                                  const u16* __restrict__ B,
                                                  void* __restrict__ Cv,
                                                  int N, int K,
                                                  const u16* __restrict__ A2,
                                                  const u16* __restrict__ B2, int K2,
                                                  long bA, long bB, long bC) {
  __shared__ __align__(16) u16 As[32768];
  __shared__ __align__(16) u16 Bs[32768];
  const int tid = threadIdx.x;
  const int bz  = blockIdx.z;
  A += (size_t)bz * bA;
  B += (size_t)bz * bB;

  // T1: bijective XCD swizzle (m204)
  const int gx = gridDim.x;
  const int nwg = gx * gridDim.y;
  int orig = blockIdx.y * gx + blockIdx.x;
  {
    int q = nwg >> 3, r = nwg & 7;
    int xcd = orig & 7, idx = orig >> 3;
    orig = (xcd < r) ? xcd * (q + 1) + idx : r * (q + 1) + (xcd - r) * q + idx;
  }
  const int brow = (orig / gx) * 256;
  const int bcol = (orig % gx) * ((EPI == 5) ? 128 : 256);
  const int bHalfOff = (EPI == 5) ? 4096 : 128;

  const int lane = tid & 63;
  const int wid  = tid >> 6;
  const int wm = wid >> 2, wn = wid & 3;
  const int srow = tid >> 3;
  const int scol = ((((tid & 7) << 4) ^ ((srow & 7) << 4)) >> 1);  // T2 swizzle (u16 units)

  f32x4 acc[8][4] = {};

  pipe256(A + (size_t)(brow + srow) * K + scol,
          B + (size_t)(bcol + srow) * K + scol, K, As, Bs, tid, wm, wn, lane, acc, bHalfOff);
  if (K2 > 0)
    pipe256(A2 + (size_t)(brow + srow) * K2 + scol,
            B2 + (size_t)(bcol + srow) * K2 + scol, K2, As, Bs, tid, wm, wn, lane, acc, 128);

  const int fr = lane & 15;
  if (EPI == 0 || EPI == 2) {
#pragma unroll
    for (int m = 0; m < 8; ++m) {
      const int mrow = (m < 4) ? (wm * 64 + m * 16) : (128 + wm * 64 + (m - 4) * 16);
#pragma unroll
      for (int j = 0; j < 4; ++j) {
        const size_t roff = (size_t)(brow + mrow + ((lane >> 4) << 2) + j) * N + bcol + fr;
#pragma unroll
        for (int n = 0; n < 4; ++n) {
          const int ncol = (n < 2) ? (wn * 32 + n * 16) : (128 + wn * 32 + (n - 2) * 16);
          if (EPI == 0) {
            ((float*)Cv + (size_t)bz * bC)[roff + ncol] = acc[m][n][j];
          } else {
            float v = acc[m][n][j];
            v = fminf(5.f, fmaxf(-5.f, v));
            ((u16*)Cv + (size_t)bz * bC)[roff + ncol] = f2bf(silu_f(v));
          }
        }
      }
    }
  } else {  // EPI == 5: up = acc[m][n], gate = acc[m][n+2]; write bf16 hidden (stride N)
    u16* Cb = (u16*)Cv;
#pragma unroll
    for (int m = 0; m < 8; ++m) {
      const int mrow = (m < 4) ? (wm * 64 + m * 16) : (128 + wm * 64 + (m - 4) * 16);
#pragma unroll
      for (int j = 0; j < 4; ++j) {
        const size_t roff = (size_t)(brow + mrow + ((lane >> 4) << 2) + j) * N + bcol + wn * 32 + fr;
#pragma unroll
        for (int n = 0; n < 2; ++n)
          Cb[roff + n * 16] = f2bf(silu_f(acc[m][n + 2][j]) * acc[m][n][j]);
      }
    }
  }
}

extern "C" void kernel_launch(void* const* d_in, const int* in_sizes, int n_in,
                              void* d_out, int out_size, void* d_ws, size_t ws_size,
                              hipStream_t stream) {
  const float* x      = (const float*)d_in[0];
  const float* W_up   = (const float*)d_in[1];
  const float* W_gate = (const float*)d_in[2];
  const float* W_down = (const float*)d_in[3];
  const float* W_pre  = (const float*)d_in[4];
  const float* W_post = (const float*)d_in[5];
  const float* W_proj = (const float*)d_in[6];
  const float* ln_g   = (const float*)d_in[7];
  const float* ln_b   = (const float*)d_in[8];
  (void)in_sizes; (void)n_in; (void)out_size; (void)ws_size;

  const int D = 2048, Hh = 4096, A_ = 256, Bn = 4, S = 2048, M = 8192;

  char* p = (char*)d_ws;
  u16* xb      = (u16*)p; p += (size_t)M * D * 2;
  u16* Wug_b   = (u16*)p; p += (size_t)2 * Hh * D * 2;  // [8192][2048]: rows 0-4095 up, 4096-8191 gate
  u16* Wdown_b = (u16*)p; p += (size_t)D * Hh * 2;
  u16* Wpre_b  = (u16*)p; p += (size_t)A_ * D * 2;
  u16* Wpost_b = (u16*)p; p += (size_t)A_ * Hh * 2;
  u16* WprojT  = (u16*)p; p += (size_t)Hh * A_ * 2;     // [256][4096] bf16 (transposed)
  u16* hidden  = (u16*)p; p += (size_t)M * Hh * 2;
  u16* scratch = (u16*)p; p += (size_t)M * Hh * 2;
  char* q = (char*)scratch;
  u16*   aw        = (u16*)q; q += (size_t)Bn * S * S * 2;
  u16*   adapt_in  = (u16*)q; q += (size_t)M * A_ * 2;
  u16*   adapt_inT = (u16*)q; q += (size_t)M * A_ * 2;
  u16*   adapt_out = (u16*)q; q += (size_t)M * A_ * 2;
  u16*   adaptb    = (u16*)q; q += (size_t)M * A_ * 2;
  u16*   Wdp_b     = (u16*)q; q += (size_t)2048 * 256 * 2;   // [2048][256] bf16 (0.1 folded)
  float* part     = (float*)Wug_b;    // [4][8192][256] f32 — alias Wug (dead after upgate GEMM)
  float* wdp_part = (float*)hidden;   // [8][2048][256] f32 — alias hidden (dead until upgate)

  // conversions (Wug = W_up then W_gate, contiguous)
  cvt7_k<<<dim3(42496), dim3(256), 0, stream>>>((const float4*)x, (const float4*)W_up,
                                                (const float4*)W_gate, (const float4*)W_down,
                                                (const float4*)W_pre, (const float4*)W_post,
                                                (ushort4*)xb);
  tcvt_k<<<dim3(64, 4), dim3(256), 0, stream>>>(W_proj, WprojT);

  // Wdp = 0.1 * (W_down @ W_proj)  [2048,256] — split-K(8) over K=4096
  gemm_sk<8><<<dim3(A_ / 128, 2048 / 128, 8), 256, 0, stream>>>(Wdown_b, WprojT, wdp_part,
                                                                2048, A_, Hh, Hh / 8, 0, 0, 2048);
  red_k<8><<<dim3(2048), 256, 0, stream>>>(wdp_part, Wdp_b, 2048, 0.1f);

  // hidden = silu(x @ W_gate^T) * (x @ W_up^T)  — single fused GEMM (EPI5)
  gemm256<5><<<dim3(Hh / 128, M / 256), 512, 0, stream>>>(xb, Wug_b, hidden,
                                                          Hh, D, nullptr, nullptr, 0, 0, 0, 0);

  // adapt_in = LN(x @ W_pre^T)  — split-K(4) + fused reduce/LN
  gemm_sk<4><<<dim3(A_ / 128, M / 128, 4), 256, 0, stream>>>(xb, Wpre_b, part,
                                                             M, A_, D, D / 4, 0, 0, M);
  red_ln_k<<<dim3(M), 256, 0, stream>>>(part, ln_g, ln_b, adapt_in, adapt_inT, M);

  // adapt_out = LN(hidden @ W_post^T)  — split-K(4)
  gemm_sk<4><<<dim3(A_ / 128, M / 128, 4), 256, 0, stream>>>(hidden, Wpost_b, part,
                                                             M, A_, Hh, Hh / 4, 0, 0, M);
  red_ln_k<<<dim3(M), 256, 0, stream>>>(part, ln_g, ln_b, adapt_out, nullptr, M);

  // aw[b] = silu(clip(adapt_in[b] @ adapt_out[b]^T, -5, 5))  — 256² pipeline, batched
  gemm256<2><<<dim3(S / 256, S / 256, Bn), 512, 0, stream>>>(adapt_in, adapt_out, aw,
                                                             S, A_, nullptr, nullptr, 0,
                                                             (long)S * A_, (long)S * A_,
                                                             (long)S * S);

  // adapt[b] = aw[b] @ adapt_in[b]  — split-K(4) over K=S, batched
  gemm_sk<4><<<dim3(A_ / 128, S / 128, Bn * 4), 256, 0, stream>>>(aw, adapt_inT, part,
                                                                  S, A_, S, S / 4,
                                                                  (long)S * S, (long)A_ * S, M);
  red_k<4><<<dim3(M), 256, 0, stream>>>(part, adaptb, M, 1.0f);

  // out = hidden @ W_down^T + adaptb @ Wdp^T   [M,D] f32  (dual-K pipeline)
  gemm256<0><<<dim3(D / 256, M / 256), 512, 0, stream>>>(hidden, Wdown_b, d_out,
                                                         D, Hh, adaptb, Wdp_b, A_, 0, 0, 0);
}